// Round 12
// baseline (220.788 us; speedup 1.0000x reference)
//
#include <hip/hip_runtime.h>
#include <cstdint>

#define NROWS_HALF 32768
#define QC_OFF 4194304            // quantized_coord offset in d_out (floats)
#define LOSS_OFF 8388608          // loss offset in d_out (floats)

// ws layout (ushort units): CODE_HI [32][64] at 0, CODE_LO [32][64] at 2048
// (code m rows = emb[m] @ lws[k], scaled by log2e, split bf16 hi/lo).
// fp32 loss accumulator at byte 8192, ticket u32 at byte 8196.
#define U_CH 0
#define U_CL 2048
#define WS_LOSS_BYTE 8192

#define X_STRIDE 68
#define LOG2E 1.4426950408889634f
#define LN2   0.6931471805599453f

typedef short short8 __attribute__((ext_vector_type(8)));
typedef float float4v __attribute__((ext_vector_type(4)));

#define MFMA16(a, b, c) __builtin_amdgcn_mfma_f32_16x16x32_bf16((a), (b), (c), 0, 0, 0)

// ---------------- Threefry-2x32 (20 rounds), matches JAX ----------------
__host__ __device__ __forceinline__ void tf2x32(uint32_t k0, uint32_t k1,
                                                uint32_t x0, uint32_t x1,
                                                uint32_t& o0, uint32_t& o1) {
  const uint32_t k2 = k0 ^ k1 ^ 0x1BD11BDAu;
#define TF_R(r) { x0 += x1; x1 = (x1 << (r)) | (x1 >> (32 - (r))); x1 ^= x0; }
  x0 += k0; x1 += k1;
  TF_R(13) TF_R(15) TF_R(26) TF_R(6)
  x0 += k1; x1 += k2 + 1u;
  TF_R(17) TF_R(29) TF_R(16) TF_R(24)
  x0 += k2; x1 += k0 + 2u;
  TF_R(13) TF_R(15) TF_R(26) TF_R(6)
  x0 += k0; x1 += k1 + 3u;
  TF_R(17) TF_R(29) TF_R(16) TF_R(24)
  x0 += k1; x1 += k2 + 4u;
  TF_R(13) TF_R(15) TF_R(26) TF_R(6)
  x0 += k2; x1 += k0 + 5u;
#undef TF_R
  o0 = x0; o1 = x1;
}

// rsq_neglog2(bits) = rsqrt(-log2(u + 1e-20)), u = (bits>>9|1.0)-1.0.
// u == cvt_f32(bits>>9) * 2^-23 exactly (both paths exact), and the fma rounds
// u+1e-20 once, identically to the reference's add. -log2 is strictly positive
// normal (u+1e-20 < 1), so no floor is needed; negation folds into v_rsq's
// source modifier. 5 VALU ops. Uniform 1/sqrt(ln2) factor cancels in all
// consumers (weights normalized by sums of same-scaled weights).
__device__ __forceinline__ float rsq_neglog2(uint32_t bits) {
  const float uf = (float)(bits >> 9);
  const float l2 = __builtin_amdgcn_logf(
      __builtin_fmaf(uf, 1.1920928955078125e-7f, 1e-20f));
  return __builtin_amdgcn_rsqf(-l2);
}

// round-to-nearest-even bf16 (returns 16-bit pattern in low bits)
__device__ __forceinline__ uint32_t rn16(float f) {
  uint32_t u = __float_as_uint(f);
  return (u + 0x7FFFu + ((u >> 16) & 1u)) >> 16;
}

__device__ __forceinline__ void split2_rn(float f0, float f1, uint32_t& hi, uint32_t& lo) {
  uint32_t h0 = rn16(f0), h1 = rn16(f1);
  hi = h0 | (h1 << 16);
  float l0 = f0 - __uint_as_float(h0 << 16);
  float l1 = f1 - __uint_as_float(h1 << 16);
  lo = rn16(l0) | (rn16(l1) << 16);
}

__device__ __forceinline__ void split8_rn(const float* p, short8& hi, short8& lo) {
  float4 f0 = *(const float4*)p;
  float4 f1 = *(const float4*)(p + 4);
  union { uint32_t u[4]; short8 s; } H, L;
  split2_rn(f0.x, f0.y, H.u[0], L.u[0]);
  split2_rn(f0.z, f0.w, H.u[1], L.u[1]);
  split2_rn(f1.x, f1.y, H.u[2], L.u[2]);
  split2_rn(f1.z, f1.w, H.u[3], L.u[3]);
  hi = H.s; lo = L.s;
}

__device__ __forceinline__ short8 as_s8(uint4 v) {
  union { uint4 u; short8 s; } c; c.u = v; return c.s;
}

// one 16-col tile of xp: 3-MFMA split-bf16 (hi+lo), B rows nb..nb+15
__device__ __forceinline__ float4v tile_mfma(const ushort* __restrict__ Vh,
                                             const ushort* __restrict__ Vl,
                                             int nb, const short8* ah, const short8* al) {
  uint4 bh0 = *(const uint4*)(Vh + nb);
  uint4 bl0 = *(const uint4*)(Vl + nb);
  float4v acc = {0.f, 0.f, 0.f, 0.f};
  acc = MFMA16(ah[0], as_s8(bh0), acc);
  acc = MFMA16(ah[0], as_s8(bl0), acc);
  acc = MFMA16(al[0], as_s8(bh0), acc);
  uint4 bh1 = *(const uint4*)(Vh + nb + 32);
  uint4 bl1 = *(const uint4*)(Vl + nb + 32);
  acc = MFMA16(ah[1], as_s8(bh1), acc);
  acc = MFMA16(ah[1], as_s8(bl1), acc);
  acc = MFMA16(al[1], as_s8(bh1), acc);
  return acc;
}

// ---------------- setup: compact code table + loss/ticket=0 ----------------
__global__ void setup_kernel(const float* __restrict__ emb, const float* __restrict__ lws,
                             ushort* __restrict__ wsu) {
  int idx = blockIdx.x * 256 + threadIdx.x;
  if (idx < 2048) {
    int m = idx >> 6, c = idx & 63, k = m >> 3;
    float a = 0.f;
    #pragma unroll
    for (int e = 0; e < 16; ++e) a += emb[m * 16 + e] * lws[(k * 16 + e) * 64 + c];
    a *= LOG2E;                      // xp logits in log2 domain
    uint32_t h = rn16(a);
    float fl = a - __uint_as_float(h << 16);
    wsu[U_CH + idx] = (ushort)h;
    wsu[U_CL + idx] = (ushort)rn16(fl);
  } else if (idx == 2048) {
    *(float*)((char*)wsu + WS_LOSS_BYTE) = 0.f;
    *(uint32_t*)((char*)wsu + WS_LOSS_BYTE + 4) = 0u;
  }
}

// ---------------- fused main kernel: 2048 blocks x 512 (8 waves, 32 rows) --------
// r11 structure + unroll-4 main loop with loads-before-threefry: 4 independent
// 72-op threefry chains + 12 outstanding ds_read_b128 per wave hide the 4-cyc
// dependent-issue gaps and LDS latency.
__global__ __launch_bounds__(512, 4) void fused_kernel(
    const float* __restrict__ inp, const float* __restrict__ emb,
    const float* __restrict__ lw, const float* __restrict__ lb,
    const ushort* __restrict__ wsu, float* __restrict__ out,
    float* __restrict__ loss_ws,
    uint32_t kc0, uint32_t kc1, uint32_t kp0, uint32_t kp1) {

  __shared__ float x_s[32 * X_STRIDE];    // input rows; later q output
  __shared__ float xp_s[32 * 32];         // codebook logits (log2 domain)
  __shared__ float4 sq4_s[16 * 3 * 12];   // [pair][axis][i] = {sqPL, i, sqPH, i}
  __shared__ float u_s[32 * 3];           // per-row u0,u1,u2
  __shared__ float swq_s[192];            // [axis][row][{S,W}]
  __shared__ float tq_s[32 * 4];          // per-row T0..T3
  __shared__ float emb_s[512];            // emb [32][16] staged
  __shared__ float wv_s[64 * 16];         // 5b weights [unit(64)][half(2)][n(8)]
  __shared__ float inv_s[128];            // 5b 1/sum  [unit(64)][half(2)]
  __shared__ float kl_s;

  const int t = threadIdx.x;
  const int lane = t & 63;
  const int w = t >> 6;                   // 0..7
  const int q = lane >> 4;
  const int mn = lane & 15;
  const int g0 = blockIdx.x * 16;

  if (t == 0) kl_s = 0.f;
  emb_s[t] = emb[t];                      // 512 floats, one per thread

  // per-lane projection coefficients (lane = channel c)
  const float pw0 = lw[lane * 3 + 0];
  const float pw1 = lw[lane * 3 + 1];
  const float pw2 = lw[lane * 3 + 2];

  // ---- load 32 input rows + per-row u = W^T x (3 butterfly reductions) ----
  #pragma unroll
  for (int it = 0; it < 4; ++it) {
    int rl = it * 8 + w;
    int row = (rl < 16) ? (g0 + rl) : (g0 + rl - 16 + NROWS_HALF);
    float v = inp[row * 64 + lane];
    x_s[rl * X_STRIDE + lane] = v;
    float u0 = v * pw0, u1 = v * pw1, u2 = v * pw2;
    #pragma unroll
    for (int off = 32; off > 0; off >>= 1) {
      u0 += __shfl_xor(u0, off);
      u1 += __shfl_xor(u1, off);
      u2 += __shfl_xor(u2, off);
    }
    if (lane == 0) {
      u_s[rl * 3 + 0] = u0; u_s[rl * 3 + 1] = u1; u_s[rl * 3 + 2] = u2;
    }
  }
  __syncthreads();

  // ---- phase2: per (row,axis): P_i = exp2((ua*g_i - 1.5*relu(ua))*log2e) ----
  if (t < 96) {
    const int row = t & 31, axis = t >> 5;
    const int pair = row & 15, half = row >> 4;
    const float ua = u_s[row * 3 + axis];
    const float b = 1.5f * fmaxf(ua, 0.f);
    float S = 0.f, W = 0.f;
    float2* slotbase = (float2*)&sq4_s[(pair * 3 + axis) * 12];
    #pragma unroll
    for (int i = 0; i < 10; ++i) {
      float gi = (float)(i * (1.5 / 9.0));
      float lg = (ua * gi - b) * LOG2E;      // <= 0
      float P = __builtin_amdgcn_exp2f(lg);
      S += P; W += lg * P;
      slotbase[i * 2 + half] = make_float2(__builtin_amdgcn_sqrtf(P), (float)i);
    }
    // pad slots (iy=10/11 reachable for c in [1000,1024)): zero weight kills them
    slotbase[10 * 2 + half] = make_float2(0.f, 10.f);
    slotbase[11 * 2 + half] = make_float2(0.f, 11.f);
    swq_s[axis * 64 + row * 2 + 0] = S;
    swq_s[axis * 64 + row * 2 + 1] = W;
  }

  // ---- A fragments for code tiles (waves 0,1,6,7; row-tile rt, code-tile ct) ----
  short8 ah[2], al[2];
  const bool codew = (w < 2) || (w >= 6);
  const int rt = (w >= 6) ? 1 : 0;
  const int ct = (w < 2) ? w : (w - 6);
  if (codew) {
    #pragma unroll
    for (int s = 0; s < 2; ++s)
      split8_rn(&x_s[(rt * 16 + mn) * X_STRIDE + s * 32 + q * 8], ah[s], al[s]);
  }
  __syncthreads();

  // ---- coord KL, closed form per row (t<32) ----
  if (t < 32) {
    float Sa = swq_s[t * 2],       Wa = swq_s[t * 2 + 1];
    float Sb = swq_s[64 + t * 2],  Wb = swq_s[64 + t * 2 + 1];
    float Sc = swq_s[128 + t * 2], Wc = swq_s[128 + t * 2 + 1];
    float kl = LN2 * ((Wa * __builtin_amdgcn_rcpf(Sa) +
                       Wb * __builtin_amdgcn_rcpf(Sb) +
                       Wc * __builtin_amdgcn_rcpf(Sc)) -
                      __builtin_amdgcn_logf(Sa * Sb * Sc)) + 6.9077552789821f;
    atomicAdd(&kl_s, kl);
  }

  // ---- code tiles: xp logits via compact code table (M rows 0..31) ----
  if (codew) {
    float4v acc = tile_mfma(wsu + U_CH, wsu + U_CL, (ct * 16 + mn) * 64 + q * 8, ah, al);
    #pragma unroll
    for (int r = 0; r < 4; ++r)
      xp_s[(rt * 16 + q * 4 + r) * 32 + ct * 16 + mn] = acc[r];
  }

  // ---- main loop: wave w owns pairs (w, w+8); pair p = rows (p, p+16) ----
  float T[16];
  #pragma unroll
  for (int z = 0; z < 16; ++z) T[z] = 0.f;

  #pragma unroll
  for (int pp = 0; pp < 2; ++pp) {
    const int p = w + pp * 8;
    const uint32_t jb = (uint32_t)(g0 + p) * 1000u;
    const float4* base4 = &sq4_s[p * 36];
    float t0l = 0.f, t1l = 0.f, t2l = 0.f, t3l = 0.f;
    float t0h = 0.f, t1h = 0.f, t2h = 0.f, t3h = 0.f;
    #pragma unroll 4
    for (int it = 0; it < 16; ++it) {
      int c = it * 64 + lane;            // < 1024; pad entries give w = 0
      // decode + table loads FIRST: ds_read latency hides under threefry
      int d10 = (c * 6554) >> 16;
      int iy  = (c * 656) >> 16;
      int kz  = c - d10 * 10;
      int jx  = d10 - iy * 10;
      float4 a4 = base4[jx], b4 = base4[12 + iy], c4 = base4[24 + kz];
      uint32_t y0, y1;
      tf2x32(kc0, kc1, jb + (uint32_t)c, jb + (uint32_t)c + 32768000u, y0, y1);
      float rL = rsq_neglog2(y0);
      float rH = rsq_neglog2(y1);
      float wL = a4.x * b4.x * (c4.x * rL);
      float wH = a4.z * b4.z * (c4.z * rH);
      t0l += wL; t1l += wL * a4.y; t2l += wL * b4.y; t3l += wL * c4.y;
      t0h += wH; t1h += wH * a4.y; t2h += wH * b4.y; t3h += wH * c4.y;
    }
    T[pp * 8 + 0] = t0l; T[pp * 8 + 1] = t1l; T[pp * 8 + 2] = t2l; T[pp * 8 + 3] = t3l;
    T[pp * 8 + 4] = t0h; T[pp * 8 + 5] = t1h; T[pp * 8 + 6] = t2h; T[pp * 8 + 7] = t3h;
  }

  // ---- butterfly-reduce all 16 accumulators across the wave ----
  #pragma unroll
  for (int off = 32; off > 0; off >>= 1) {
    #pragma unroll
    for (int z = 0; z < 16; ++z) T[z] += __shfl_xor(T[z], off);
  }
  if (lane == 0) {
    #pragma unroll
    for (int pp = 0; pp < 2; ++pp) {
      int rl = w + pp * 8, rh = rl + 16;
      #pragma unroll
      for (int cmp = 0; cmp < 4; ++cmp) {
        tq_s[rl * 4 + cmp] = T[pp * 8 + cmp];
        tq_s[rh * 4 + cmp] = T[pp * 8 + 4 + cmp];
      }
    }
  }
  __syncthreads();

  // ---- qc epilogue: rank-4 reconstruction, fp32 throughout ----
  {
    const int d = t & 63, rb = t >> 6;     // rb 0..7
    const float l0 = lw[d * 3 + 0], l1 = lw[d * 3 + 1], l2 = lw[d * 3 + 2];
    const float lbd = lb[d];
    const float stepf = (float)(1.5 / 9.0);
    #pragma unroll
    for (int kk = 0; kk < 4; ++kk) {
      int m = rb + kk * 8;                 // 0..31
      float T0v = tq_s[m * 4 + 0], T1v = tq_s[m * 4 + 1];
      float T2v = tq_s[m * 4 + 2], T3v = tq_s[m * 4 + 3];
      float num = (T1v * l0 + T2v * l1 + T3v * l2) * stepf + T0v * lbd;
      int grow = (m < 16) ? (g0 + m) : (g0 + m - 16 + NROWS_HALF);
      out[QC_OFF + grow * 64 + d] = num * __builtin_amdgcn_rcpf(T0v);
    }
  }

  // ---- 5b phase A: one thread per (unit u_, element n); 64 units x 8 ----
  {
    const int u_ = t >> 3, n = t & 7;      // u_ 0..63
    const int p = u_ >> 2, k = u_ & 3;     // p 0..15
    const float xpA = xp_s[p * 32 + k * 8 + n];
    const float xpB = xp_s[(p + 16) * 32 + k * 8 + n];
    float mA = xpA, mB = xpB;
    #pragma unroll
    for (int off = 1; off < 8; off <<= 1) {
      mA = fmaxf(mA, __shfl_xor(mA, off));
      mB = fmaxf(mB, __shfl_xor(mB, off));
    }
    float eA = __builtin_amdgcn_exp2f(xpA - mA);
    float eB = __builtin_amdgcn_exp2f(xpB - mB);
    float s0A = eA, s1A = eA * xpA, s0B = eB, s1B = eB * xpB;
    const uint32_t base = (uint32_t)(g0 + p) * 32u + (uint32_t)k * 8u;
    uint32_t y0, y1;
    tf2x32(kp0, kp1, base + (uint32_t)n, base + (uint32_t)n + 1048576u, y0, y1);
    float wvA = __builtin_amdgcn_exp2f((xpA - mA) * 0.5f) * rsq_neglog2(y0);
    float wvB = __builtin_amdgcn_exp2f((xpB - mB) * 0.5f) * rsq_neglog2(y1);
    float swA = wvA, swB = wvB;
    #pragma unroll
    for (int off = 1; off < 8; off <<= 1) {
      s0A += __shfl_xor(s0A, off);
      s1A += __shfl_xor(s1A, off);
      s0B += __shfl_xor(s0B, off);
      s1B += __shfl_xor(s1B, off);
      swA += __shfl_xor(swA, off);
      swB += __shfl_xor(swB, off);
    }
    wv_s[u_ * 16 + n] = wvA;
    wv_s[u_ * 16 + 8 + n] = wvB;
    if (n == 0) {
      inv_s[u_ * 2 + 0] = __builtin_amdgcn_rcpf(swA);
      inv_s[u_ * 2 + 1] = __builtin_amdgcn_rcpf(swB);
      atomicAdd(&kl_s,
          LN2 * ((s1A * __builtin_amdgcn_rcpf(s0A) - mA) - __builtin_amdgcn_logf(s0A)) +
          LN2 * ((s1B * __builtin_amdgcn_rcpf(s0B) - mB) - __builtin_amdgcn_logf(s0B)) +
          4.1588830833596715f);
    }
  }
  __syncthreads();

  // ---- 5b phase B: thread = (row r, dim e); q = sum_n wv*emb / sum ----
  float* q_s = x_s;   // x dead (frags extracted pre-loop)
  {
    const int r = t >> 4, e = t & 15;      // r 0..31
    const int p = r & 15, h = r >> 4;
    #pragma unroll
    for (int k = 0; k < 4; ++k) {
      const int u_ = p * 4 + k;
      float aa = 0.f;
      #pragma unroll
      for (int n = 0; n < 8; ++n)
        aa += wv_s[u_ * 16 + h * 8 + n] * emb_s[(k * 8 + n) * 16 + e];
      q_s[r * X_STRIDE + k * 16 + e] = aa * inv_s[u_ * 2 + h];
    }
  }
  __syncthreads();

  // ---- copyout quantized (coalesced) + loss; last block finalizes loss ----
  #pragma unroll
  for (int it = 0; it < 4; ++it) {
    int idx = it * 512 + t;
    int rl = idx >> 6, c = idx & 63;
    int row = (rl < 16) ? (g0 + rl) : (g0 + rl - 16 + NROWS_HALF);
    out[row * 64 + c] = q_s[rl * X_STRIDE + c];
  }
  if (t == 0) {
    atomicAdd(loss_ws, kl_s);
    __threadfence();
    uint32_t tk = atomicAdd((uint32_t*)loss_ws + 1, 1u);
    if (tk == 2047u) {
      __threadfence();
      out[LOSS_OFF] = atomicAdd(loss_ws, 0.0f) * 0.2f;
    }
  }
}

extern "C" void kernel_launch(void* const* d_in, const int* in_sizes, int n_in,
                              void* d_out, int out_size, void* d_ws, size_t ws_size,
                              hipStream_t stream) {
  const float* inp  = (const float*)d_in[0];   // [32,2048,64]
  const float* lw   = (const float*)d_in[1];   // [64,3]
  const float* lb   = (const float*)d_in[2];   // [64]
  const float* emb  = (const float*)d_in[3];   // [32,16] normalized
  const float* lws  = (const float*)d_in[4];   // [4,16,64]
  float* out = (float*)d_out;
  ushort* wsu = (ushort*)d_ws;
  float* loss_ws = (float*)((char*)d_ws + WS_LOSS_BYTE);

  // JAX PRNG keys: key(42) -> [0,42]; split = threefry over iota(4)
  uint32_t a0, b0, a1, b1;
  tf2x32(0u, 42u, 0u, 2u, a0, b0);
  tf2x32(0u, 42u, 1u, 3u, a1, b1);
  const uint32_t kc0 = a0, kc1 = a1;   // coord-noise key
  const uint32_t kp0 = b0, kp1 = b1;   // codebook-noise key

  setup_kernel<<<9, 256, 0, stream>>>(emb, lws, wsu);
  fused_kernel<<<2048, 512, 0, stream>>>(inp, emb, lw, lb, wsu, out, loss_ws,
                                         kc0, kc1, kp0, kp1);
}

// Round 13
// 216.279 us; speedup vs baseline: 1.0209x; 1.0209x over previous
//
#include <hip/hip_runtime.h>
#include <cstdint>

#define NROWS_HALF 32768
#define QC_OFF 4194304            // quantized_coord offset in d_out (floats)
#define LOSS_OFF 8388608          // loss offset in d_out (floats)

// ws layout (ushort units): CODE_HI [32][64] at 0, CODE_LO [32][64] at 2048
// (code m rows = emb[m] @ lws[k], scaled by log2e, split bf16 hi/lo).
// fp32 loss accumulator at byte 8192, ticket u32 at byte 8196.
#define U_CH 0
#define U_CL 2048
#define WS_LOSS_BYTE 8192

#define X_STRIDE 68
#define LOG2E 1.4426950408889634f
#define LN2   0.6931471805599453f

typedef short short8 __attribute__((ext_vector_type(8)));
typedef float float4v __attribute__((ext_vector_type(4)));

#define MFMA16(a, b, c) __builtin_amdgcn_mfma_f32_16x16x32_bf16((a), (b), (c), 0, 0, 0)

// ---------------- Threefry-2x32 (20 rounds), matches JAX ----------------
__host__ __device__ __forceinline__ void tf2x32(uint32_t k0, uint32_t k1,
                                                uint32_t x0, uint32_t x1,
                                                uint32_t& o0, uint32_t& o1) {
  const uint32_t k2 = k0 ^ k1 ^ 0x1BD11BDAu;
#define TF_R(r) { x0 += x1; x1 = (x1 << (r)) | (x1 >> (32 - (r))); x1 ^= x0; }
  x0 += k0; x1 += k1;
  TF_R(13) TF_R(15) TF_R(26) TF_R(6)
  x0 += k1; x1 += k2 + 1u;
  TF_R(17) TF_R(29) TF_R(16) TF_R(24)
  x0 += k2; x1 += k0 + 2u;
  TF_R(13) TF_R(15) TF_R(26) TF_R(6)
  x0 += k0; x1 += k1 + 3u;
  TF_R(17) TF_R(29) TF_R(16) TF_R(24)
  x0 += k1; x1 += k2 + 4u;
  TF_R(13) TF_R(15) TF_R(26) TF_R(6)
  x0 += k2; x1 += k0 + 5u;
#undef TF_R
  o0 = x0; o1 = x1;
}

// rsq_neglog2(bits) = rsqrt(-log2(u + 1e-20)), u = (bits>>9|1.0)-1.0.
// u == cvt_f32(bits>>9) * 2^-23 exactly (both paths exact), and the fma rounds
// u+1e-20 once, identically to the reference's add. -log2 is strictly positive
// normal (u+1e-20 < 1), so no floor is needed; negation folds into v_rsq's
// source modifier. 5 VALU ops. Uniform 1/sqrt(ln2) factor cancels in all
// consumers (weights normalized by sums of same-scaled weights).
__device__ __forceinline__ float rsq_neglog2(uint32_t bits) {
  const float uf = (float)(bits >> 9);
  const float l2 = __builtin_amdgcn_logf(
      __builtin_fmaf(uf, 1.1920928955078125e-7f, 1e-20f));
  return __builtin_amdgcn_rsqf(-l2);
}

// round-to-nearest-even bf16 (returns 16-bit pattern in low bits)
__device__ __forceinline__ uint32_t rn16(float f) {
  uint32_t u = __float_as_uint(f);
  return (u + 0x7FFFu + ((u >> 16) & 1u)) >> 16;
}

__device__ __forceinline__ void split2_rn(float f0, float f1, uint32_t& hi, uint32_t& lo) {
  uint32_t h0 = rn16(f0), h1 = rn16(f1);
  hi = h0 | (h1 << 16);
  float l0 = f0 - __uint_as_float(h0 << 16);
  float l1 = f1 - __uint_as_float(h1 << 16);
  lo = rn16(l0) | (rn16(l1) << 16);
}

__device__ __forceinline__ void split8_rn(const float* p, short8& hi, short8& lo) {
  float4 f0 = *(const float4*)p;
  float4 f1 = *(const float4*)(p + 4);
  union { uint32_t u[4]; short8 s; } H, L;
  split2_rn(f0.x, f0.y, H.u[0], L.u[0]);
  split2_rn(f0.z, f0.w, H.u[1], L.u[1]);
  split2_rn(f1.x, f1.y, H.u[2], L.u[2]);
  split2_rn(f1.z, f1.w, H.u[3], L.u[3]);
  hi = H.s; lo = L.s;
}

__device__ __forceinline__ short8 as_s8(uint4 v) {
  union { uint4 u; short8 s; } c; c.u = v; return c.s;
}

// one 16-col tile of xp: 3-MFMA split-bf16 (hi+lo), B rows nb..nb+15
__device__ __forceinline__ float4v tile_mfma(const ushort* __restrict__ Vh,
                                             const ushort* __restrict__ Vl,
                                             int nb, const short8* ah, const short8* al) {
  uint4 bh0 = *(const uint4*)(Vh + nb);
  uint4 bl0 = *(const uint4*)(Vl + nb);
  float4v acc = {0.f, 0.f, 0.f, 0.f};
  acc = MFMA16(ah[0], as_s8(bh0), acc);
  acc = MFMA16(ah[0], as_s8(bl0), acc);
  acc = MFMA16(al[0], as_s8(bh0), acc);
  uint4 bh1 = *(const uint4*)(Vh + nb + 32);
  uint4 bl1 = *(const uint4*)(Vl + nb + 32);
  acc = MFMA16(ah[1], as_s8(bh1), acc);
  acc = MFMA16(ah[1], as_s8(bl1), acc);
  acc = MFMA16(al[1], as_s8(bh1), acc);
  return acc;
}

// ---------------- setup: compact code table + loss/ticket=0 ----------------
__global__ void setup_kernel(const float* __restrict__ emb, const float* __restrict__ lws,
                             ushort* __restrict__ wsu) {
  int idx = blockIdx.x * 256 + threadIdx.x;
  if (idx < 2048) {
    int m = idx >> 6, c = idx & 63, k = m >> 3;
    float a = 0.f;
    #pragma unroll
    for (int e = 0; e < 16; ++e) a += emb[m * 16 + e] * lws[(k * 16 + e) * 64 + c];
    a *= LOG2E;                      // xp logits in log2 domain
    uint32_t h = rn16(a);
    float fl = a - __uint_as_float(h << 16);
    wsu[U_CH + idx] = (ushort)h;
    wsu[U_CL + idx] = (ushort)rn16(fl);
  } else if (idx == 2048) {
    *(float*)((char*)wsu + WS_LOSS_BYTE) = 0.f;
    *(uint32_t*)((char*)wsu + WS_LOSS_BYTE + 4) = 0u;
  }
}

// ---------------- fused main kernel: 2048 blocks x 512 (8 waves, 32 rows) --------
// Separable coordinate path (r9 structure) + 5-op gumbel. Best verified: 159.5 us.
__global__ __launch_bounds__(512, 4) void fused_kernel(
    const float* __restrict__ inp, const float* __restrict__ emb,
    const float* __restrict__ lw, const float* __restrict__ lb,
    const ushort* __restrict__ wsu, float* __restrict__ out,
    float* __restrict__ loss_ws,
    uint32_t kc0, uint32_t kc1, uint32_t kp0, uint32_t kp1) {

  __shared__ float x_s[32 * X_STRIDE];    // input rows; later q output
  __shared__ float xp_s[32 * 32];         // codebook logits (log2 domain)
  __shared__ float4 sq4_s[16 * 3 * 12];   // [pair][axis][i] = {sqPL, i, sqPH, i}
  __shared__ float u_s[32 * 3];           // per-row u0,u1,u2
  __shared__ float swq_s[192];            // [axis][row][{S,W}]
  __shared__ float tq_s[32 * 4];          // per-row T0..T3
  __shared__ float emb_s[512];            // emb [32][16] staged
  __shared__ float wv_s[64 * 16];         // 5b weights [unit(64)][half(2)][n(8)]
  __shared__ float inv_s[128];            // 5b 1/sum  [unit(64)][half(2)]
  __shared__ float kl_s;

  const int t = threadIdx.x;
  const int lane = t & 63;
  const int w = t >> 6;                   // 0..7
  const int q = lane >> 4;
  const int mn = lane & 15;
  const int g0 = blockIdx.x * 16;

  if (t == 0) kl_s = 0.f;
  emb_s[t] = emb[t];                      // 512 floats, one per thread

  // per-lane projection coefficients (lane = channel c)
  const float pw0 = lw[lane * 3 + 0];
  const float pw1 = lw[lane * 3 + 1];
  const float pw2 = lw[lane * 3 + 2];

  // ---- load 32 input rows + per-row u = W^T x (3 butterfly reductions) ----
  #pragma unroll
  for (int it = 0; it < 4; ++it) {
    int rl = it * 8 + w;
    int row = (rl < 16) ? (g0 + rl) : (g0 + rl - 16 + NROWS_HALF);
    float v = inp[row * 64 + lane];
    x_s[rl * X_STRIDE + lane] = v;
    float u0 = v * pw0, u1 = v * pw1, u2 = v * pw2;
    #pragma unroll
    for (int off = 32; off > 0; off >>= 1) {
      u0 += __shfl_xor(u0, off);
      u1 += __shfl_xor(u1, off);
      u2 += __shfl_xor(u2, off);
    }
    if (lane == 0) {
      u_s[rl * 3 + 0] = u0; u_s[rl * 3 + 1] = u1; u_s[rl * 3 + 2] = u2;
    }
  }
  __syncthreads();

  // ---- phase2: per (row,axis): P_i = exp2((ua*g_i - 1.5*relu(ua))*log2e) ----
  if (t < 96) {
    const int row = t & 31, axis = t >> 5;
    const int pair = row & 15, half = row >> 4;
    const float ua = u_s[row * 3 + axis];
    const float b = 1.5f * fmaxf(ua, 0.f);
    float S = 0.f, W = 0.f;
    float2* slotbase = (float2*)&sq4_s[(pair * 3 + axis) * 12];
    #pragma unroll
    for (int i = 0; i < 10; ++i) {
      float gi = (float)(i * (1.5 / 9.0));
      float lg = (ua * gi - b) * LOG2E;      // <= 0
      float P = __builtin_amdgcn_exp2f(lg);
      S += P; W += lg * P;
      slotbase[i * 2 + half] = make_float2(__builtin_amdgcn_sqrtf(P), (float)i);
    }
    // pad slots (iy=10/11 reachable for c in [1000,1024)): zero weight kills them
    slotbase[10 * 2 + half] = make_float2(0.f, 10.f);
    slotbase[11 * 2 + half] = make_float2(0.f, 11.f);
    swq_s[axis * 64 + row * 2 + 0] = S;
    swq_s[axis * 64 + row * 2 + 1] = W;
  }

  // ---- A fragments for code tiles (waves 0,1,6,7; row-tile rt, code-tile ct) ----
  short8 ah[2], al[2];
  const bool codew = (w < 2) || (w >= 6);
  const int rt = (w >= 6) ? 1 : 0;
  const int ct = (w < 2) ? w : (w - 6);
  if (codew) {
    #pragma unroll
    for (int s = 0; s < 2; ++s)
      split8_rn(&x_s[(rt * 16 + mn) * X_STRIDE + s * 32 + q * 8], ah[s], al[s]);
  }
  __syncthreads();

  // ---- coord KL, closed form per row (t<32) ----
  if (t < 32) {
    float Sa = swq_s[t * 2],       Wa = swq_s[t * 2 + 1];
    float Sb = swq_s[64 + t * 2],  Wb = swq_s[64 + t * 2 + 1];
    float Sc = swq_s[128 + t * 2], Wc = swq_s[128 + t * 2 + 1];
    float kl = LN2 * ((Wa * __builtin_amdgcn_rcpf(Sa) +
                       Wb * __builtin_amdgcn_rcpf(Sb) +
                       Wc * __builtin_amdgcn_rcpf(Sc)) -
                      __builtin_amdgcn_logf(Sa * Sb * Sc)) + 6.9077552789821f;
    atomicAdd(&kl_s, kl);
  }

  // ---- code tiles: xp logits via compact code table (M rows 0..31) ----
  if (codew) {
    float4v acc = tile_mfma(wsu + U_CH, wsu + U_CL, (ct * 16 + mn) * 64 + q * 8, ah, al);
    #pragma unroll
    for (int r = 0; r < 4; ++r)
      xp_s[(rt * 16 + q * 4 + r) * 32 + ct * 16 + mn] = acc[r];
  }

  // ---- main loop: wave w owns pairs (w, w+8); pair p = rows (p, p+16) ----
  float T[16];
  #pragma unroll
  for (int z = 0; z < 16; ++z) T[z] = 0.f;

  #pragma unroll
  for (int pp = 0; pp < 2; ++pp) {
    const int p = w + pp * 8;
    const uint32_t jb = (uint32_t)(g0 + p) * 1000u;
    const float4* base4 = &sq4_s[p * 36];
    float t0l = 0.f, t1l = 0.f, t2l = 0.f, t3l = 0.f;
    float t0h = 0.f, t1h = 0.f, t2h = 0.f, t3h = 0.f;
    #pragma unroll 2
    for (int it = 0; it < 16; ++it) {
      int c = it * 64 + lane;            // < 1024; pad entries give w = 0
      uint32_t y0, y1;
      tf2x32(kc0, kc1, jb + (uint32_t)c, jb + (uint32_t)c + 32768000u, y0, y1);
      int d10 = (c * 6554) >> 16;
      int iy  = (c * 656) >> 16;
      int kz  = c - d10 * 10;
      int jx  = d10 - iy * 10;
      float4 a4 = base4[jx], b4 = base4[12 + iy], c4 = base4[24 + kz];
      float rL = rsq_neglog2(y0);
      float rH = rsq_neglog2(y1);
      float wL = a4.x * b4.x * (c4.x * rL);
      float wH = a4.z * b4.z * (c4.z * rH);
      t0l += wL; t1l += wL * a4.y; t2l += wL * b4.y; t3l += wL * c4.y;
      t0h += wH; t1h += wH * a4.y; t2h += wH * b4.y; t3h += wH * c4.y;
    }
    T[pp * 8 + 0] = t0l; T[pp * 8 + 1] = t1l; T[pp * 8 + 2] = t2l; T[pp * 8 + 3] = t3l;
    T[pp * 8 + 4] = t0h; T[pp * 8 + 5] = t1h; T[pp * 8 + 6] = t2h; T[pp * 8 + 7] = t3h;
  }

  // ---- butterfly-reduce all 16 accumulators across the wave ----
  #pragma unroll
  for (int off = 32; off > 0; off >>= 1) {
    #pragma unroll
    for (int z = 0; z < 16; ++z) T[z] += __shfl_xor(T[z], off);
  }
  if (lane == 0) {
    #pragma unroll
    for (int pp = 0; pp < 2; ++pp) {
      int rl = w + pp * 8, rh = rl + 16;
      #pragma unroll
      for (int cmp = 0; cmp < 4; ++cmp) {
        tq_s[rl * 4 + cmp] = T[pp * 8 + cmp];
        tq_s[rh * 4 + cmp] = T[pp * 8 + 4 + cmp];
      }
    }
  }
  __syncthreads();

  // ---- qc epilogue: rank-4 reconstruction, fp32 throughout ----
  {
    const int d = t & 63, rb = t >> 6;     // rb 0..7
    const float l0 = lw[d * 3 + 0], l1 = lw[d * 3 + 1], l2 = lw[d * 3 + 2];
    const float lbd = lb[d];
    const float stepf = (float)(1.5 / 9.0);
    #pragma unroll
    for (int kk = 0; kk < 4; ++kk) {
      int m = rb + kk * 8;                 // 0..31
      float T0v = tq_s[m * 4 + 0], T1v = tq_s[m * 4 + 1];
      float T2v = tq_s[m * 4 + 2], T3v = tq_s[m * 4 + 3];
      float num = (T1v * l0 + T2v * l1 + T3v * l2) * stepf + T0v * lbd;
      int grow = (m < 16) ? (g0 + m) : (g0 + m - 16 + NROWS_HALF);
      out[QC_OFF + grow * 64 + d] = num * __builtin_amdgcn_rcpf(T0v);
    }
  }

  // ---- 5b phase A: one thread per (unit u_, element n); 64 units x 8 ----
  {
    const int u_ = t >> 3, n = t & 7;      // u_ 0..63
    const int p = u_ >> 2, k = u_ & 3;     // p 0..15
    const float xpA = xp_s[p * 32 + k * 8 + n];
    const float xpB = xp_s[(p + 16) * 32 + k * 8 + n];
    float mA = xpA, mB = xpB;
    #pragma unroll
    for (int off = 1; off < 8; off <<= 1) {
      mA = fmaxf(mA, __shfl_xor(mA, off));
      mB = fmaxf(mB, __shfl_xor(mB, off));
    }
    float eA = __builtin_amdgcn_exp2f(xpA - mA);
    float eB = __builtin_amdgcn_exp2f(xpB - mB);
    float s0A = eA, s1A = eA * xpA, s0B = eB, s1B = eB * xpB;
    const uint32_t base = (uint32_t)(g0 + p) * 32u + (uint32_t)k * 8u;
    uint32_t y0, y1;
    tf2x32(kp0, kp1, base + (uint32_t)n, base + (uint32_t)n + 1048576u, y0, y1);
    float wvA = __builtin_amdgcn_exp2f((xpA - mA) * 0.5f) * rsq_neglog2(y0);
    float wvB = __builtin_amdgcn_exp2f((xpB - mB) * 0.5f) * rsq_neglog2(y1);
    float swA = wvA, swB = wvB;
    #pragma unroll
    for (int off = 1; off < 8; off <<= 1) {
      s0A += __shfl_xor(s0A, off);
      s1A += __shfl_xor(s1A, off);
      s0B += __shfl_xor(s0B, off);
      s1B += __shfl_xor(s1B, off);
      swA += __shfl_xor(swA, off);
      swB += __shfl_xor(swB, off);
    }
    wv_s[u_ * 16 + n] = wvA;
    wv_s[u_ * 16 + 8 + n] = wvB;
    if (n == 0) {
      inv_s[u_ * 2 + 0] = __builtin_amdgcn_rcpf(swA);
      inv_s[u_ * 2 + 1] = __builtin_amdgcn_rcpf(swB);
      atomicAdd(&kl_s,
          LN2 * ((s1A * __builtin_amdgcn_rcpf(s0A) - mA) - __builtin_amdgcn_logf(s0A)) +
          LN2 * ((s1B * __builtin_amdgcn_rcpf(s0B) - mB) - __builtin_amdgcn_logf(s0B)) +
          4.1588830833596715f);
    }
  }
  __syncthreads();

  // ---- 5b phase B: thread = (row r, dim e); q = sum_n wv*emb / sum ----
  float* q_s = x_s;   // x dead (frags extracted pre-loop)
  {
    const int r = t >> 4, e = t & 15;      // r 0..31
    const int p = r & 15, h = r >> 4;
    #pragma unroll
    for (int k = 0; k < 4; ++k) {
      const int u_ = p * 4 + k;
      float aa = 0.f;
      #pragma unroll
      for (int n = 0; n < 8; ++n)
        aa += wv_s[u_ * 16 + h * 8 + n] * emb_s[(k * 8 + n) * 16 + e];
      q_s[r * X_STRIDE + k * 16 + e] = aa * inv_s[u_ * 2 + h];
    }
  }
  __syncthreads();

  // ---- copyout quantized (coalesced) + loss; last block finalizes loss ----
  #pragma unroll
  for (int it = 0; it < 4; ++it) {
    int idx = it * 512 + t;
    int rl = idx >> 6, c = idx & 63;
    int row = (rl < 16) ? (g0 + rl) : (g0 + rl - 16 + NROWS_HALF);
    out[row * 64 + c] = q_s[rl * X_STRIDE + c];
  }
  if (t == 0) {
    atomicAdd(loss_ws, kl_s);
    __threadfence();
    uint32_t tk = atomicAdd((uint32_t*)loss_ws + 1, 1u);
    if (tk == 2047u) {
      __threadfence();
      out[LOSS_OFF] = atomicAdd(loss_ws, 0.0f) * 0.2f;
    }
  }
}

extern "C" void kernel_launch(void* const* d_in, const int* in_sizes, int n_in,
                              void* d_out, int out_size, void* d_ws, size_t ws_size,
                              hipStream_t stream) {
  const float* inp  = (const float*)d_in[0];   // [32,2048,64]
  const float* lw   = (const float*)d_in[1];   // [64,3]
  const float* lb   = (const float*)d_in[2];   // [64]
  const float* emb  = (const float*)d_in[3];   // [32,16] normalized
  const float* lws  = (const float*)d_in[4];   // [4,16,64]
  float* out = (float*)d_out;
  ushort* wsu = (ushort*)d_ws;
  float* loss_ws = (float*)((char*)d_ws + WS_LOSS_BYTE);

  // JAX PRNG keys: key(42) -> [0,42]; split = threefry over iota(4)
  uint32_t a0, b0, a1, b1;
  tf2x32(0u, 42u, 0u, 2u, a0, b0);
  tf2x32(0u, 42u, 1u, 3u, a1, b1);
  const uint32_t kc0 = a0, kc1 = a1;   // coord-noise key
  const uint32_t kp0 = b0, kp1 = b1;   // codebook-noise key

  setup_kernel<<<9, 256, 0, stream>>>(emb, lws, wsu);
  fused_kernel<<<2048, 512, 0, stream>>>(inp, emb, lw, lb, wsu, out, loss_ws,
                                         kc0, kc1, kp0, kp1);
}